// Round 4
// baseline (153.576 us; speedup 1.0000x reference)
//
#include <hip/hip_runtime.h>
#include <hip/hip_bf16.h>

#define D_SRC 256
#define D_REL 128

typedef __bf16 bf16x8 __attribute__((ext_vector_type(8)));
typedef float f32x4 __attribute__((ext_vector_type(4)));
typedef float f32x16 __attribute__((ext_vector_type(16)));

// ---------------- zero scratch ----------------
__global__ void zero_kernel(int* __restrict__ p, int n) {
    int i = blockIdx.x * 256 + threadIdx.x;
    if (i < n) p[i] = 0;
}

// ---------------- prep: arrange W (fp32 [256][128]) into 32x32x16 B-fragment order ----------------
// Wt[(ks*4+n)*64 + lane] = bf16x8 { W[ks*16 + (lane>>5)*8 + j][n*32 + (lane&31)] , j=0..7 }
__global__ __launch_bounds__(64) void prep_w_kernel(const float* __restrict__ W,
                                                    bf16x8* __restrict__ Wt) {
    int c = blockIdx.x;            // 0..63 = ks*4 + n
    int ks = c >> 2, n = c & 3;
    int lane = threadIdx.x;
    int col = n * 32 + (lane & 31);
    int k0 = ks * 16 + (lane >> 5) * 8;
    bf16x8 v;
#pragma unroll
    for (int j = 0; j < 8; ++j) v[j] = (__bf16)W[(size_t)(k0 + j) * D_REL + col];
    Wt[c * 64 + lane] = v;
}

// ---------------- projection via 32x32x16 bf16 MFMA, no LDS, no barrier ----------------
// 256 threads = 4 waves; each wave computes 32 rows x 128 cols.
// B fragments read directly from global Wt (64 KB, L2-resident).
__global__ __launch_bounds__(256, 4) void proj_mfma_kernel(
    const float* __restrict__ x, const bf16x8* __restrict__ Wt,
    float* __restrict__ out, unsigned short* __restrict__ out_bf, int M) {
    int tid = threadIdx.x;
    int wave = tid >> 6, lane = tid & 63;
    int half = lane >> 5;          // 0/1
    int r31 = lane & 31;
    int row = blockIdx.x * 128 + wave * 32 + r31;
    int rowc = min(row, M - 1);
    const float* xr = x + (size_t)rowc * D_SRC + half * 8;

    f32x16 acc[4];
#pragma unroll
    for (int n = 0; n < 4; ++n) acc[n] = (f32x16)(0.f);

    // prologue: A for ks=0
    f32x4 a0 = *(const f32x4*)(xr);
    f32x4 a1 = *(const f32x4*)(xr + 4);

#pragma unroll
    for (int ks = 0; ks < 16; ++ks) {
        // B fragments for this step (L2 hits)
        bf16x8 b0 = Wt[(ks * 4 + 0) * 64 + lane];
        bf16x8 b1 = Wt[(ks * 4 + 1) * 64 + lane];
        bf16x8 b2 = Wt[(ks * 4 + 2) * 64 + lane];
        bf16x8 b3 = Wt[(ks * 4 + 3) * 64 + lane];
        // prefetch A for next step (hide HBM latency under MFMAs)
        f32x4 na0, na1;
        if (ks < 15) {
            na0 = *(const f32x4*)(xr + (ks + 1) * 16);
            na1 = *(const f32x4*)(xr + (ks + 1) * 16 + 4);
        }
        bf16x8 af;
        af[0] = (__bf16)a0[0]; af[1] = (__bf16)a0[1];
        af[2] = (__bf16)a0[2]; af[3] = (__bf16)a0[3];
        af[4] = (__bf16)a1[0]; af[5] = (__bf16)a1[1];
        af[6] = (__bf16)a1[2]; af[7] = (__bf16)a1[3];
        acc[0] = __builtin_amdgcn_mfma_f32_32x32x16_bf16(af, b0, acc[0], 0, 0, 0);
        acc[1] = __builtin_amdgcn_mfma_f32_32x32x16_bf16(af, b1, acc[1], 0, 0, 0);
        acc[2] = __builtin_amdgcn_mfma_f32_32x32x16_bf16(af, b2, acc[2], 0, 0, 0);
        acc[3] = __builtin_amdgcn_mfma_f32_32x32x16_bf16(af, b3, acc[3], 0, 0, 0);
        if (ks < 15) { a0 = na0; a1 = na1; }
    }

    // store: row = base + (reg&3) + 8*(reg>>2) + 4*half, col = n*32 + r31
    int rbase = blockIdx.x * 128 + wave * 32 + 4 * half;
#pragma unroll
    for (int n = 0; n < 4; ++n) {
#pragma unroll
        for (int reg = 0; reg < 16; ++reg) {
            int r = rbase + (reg & 3) + 8 * (reg >> 2);
            if (r < M) {
                float v = acc[n][reg];
                size_t o = (size_t)r * D_REL + n * 32 + r31;
                out[o] = v;
                out_bf[o] = __bfloat16_as_ushort(__float2bfloat16(v));
            }
        }
    }
}

// ---------------- degree count + per-edge bucket position ----------------
__global__ void count_kernel(const int* __restrict__ edge_dst, int* __restrict__ deg_i,
                             int* __restrict__ pos_arr, int E) {
    int e = blockIdx.x * 256 + threadIdx.x;
    if (e < E) pos_arr[e] = atomicAdd(&deg_i[edge_dst[e]], 1);
}

// ---------------- 2-level exclusive scan ----------------
__global__ __launch_bounds__(1024) void scan_blocks(
    const int* __restrict__ deg_i, int* __restrict__ incl,
    int* __restrict__ bsums, int n) {
    int i = blockIdx.x * 1024 + threadIdx.x;
    int v = (i < n) ? deg_i[i] : 0;
    int lane = threadIdx.x & 63;
    int wid = threadIdx.x >> 6;
    int x = v;
#pragma unroll
    for (int off = 1; off < 64; off <<= 1) {
        int y = __shfl_up(x, off, 64);
        if (lane >= off) x += y;
    }
    __shared__ int wsum[16];
    if (lane == 63) wsum[wid] = x;
    __syncthreads();
    if (wid == 0 && lane < 16) {
        int s = wsum[lane];
#pragma unroll
        for (int off = 1; off < 16; off <<= 1) {
            int y = __shfl_up(s, off, 64);
            if (lane >= off) s += y;
        }
        wsum[lane] = s;
    }
    __syncthreads();
    int add = (wid > 0) ? wsum[wid - 1] : 0;
    x += add;
    if (i < n) incl[i] = x;
    if (threadIdx.x == 1023) bsums[blockIdx.x] = x;
}

__global__ __launch_bounds__(128) void scan_sums(int* __restrict__ bs, int nb) {
    __shared__ int tmp[128];
    int t = threadIdx.x;
    int v = (t < nb) ? bs[t] : 0;
    tmp[t] = v;
    __syncthreads();
    for (int off = 1; off < 128; off <<= 1) {
        int y = 0;
        if (t >= off) y = tmp[t - off];
        __syncthreads();
        tmp[t] += y;
        __syncthreads();
    }
    if (t < nb) bs[t] = tmp[t] - v;  // exclusive
}

__global__ __launch_bounds__(1024) void finalize_kernel(
    const int* __restrict__ deg_i, const int* __restrict__ incl,
    const int* __restrict__ bsums, int* __restrict__ row_start,
    float* __restrict__ deg_out, int n, int E) {
    int i = blockIdx.x * 1024 + threadIdx.x;
    if (i < n) {
        int off = bsums[blockIdx.x];
        row_start[i] = off + incl[i] - deg_i[i];
        deg_out[i] = (float)max(deg_i[i], 1);
    }
    if (i == 0) row_start[n] = E;
}

// ---------------- bucket fill (atomic-free) ----------------
__global__ void fill_kernel(const int* __restrict__ edge_src,
                            const int* __restrict__ edge_dst,
                            const int* __restrict__ row_start,
                            const int* __restrict__ pos_arr,
                            int* __restrict__ bucket, int E) {
    int e = blockIdx.x * 256 + threadIdx.x;
    if (e < E) {
        int d = edge_dst[e];
        bucket[row_start[d] + pos_arr[e]] = edge_src[e];
    }
}

// ---------------- gather: one wave per dst row, bf16 source, 4-deep pipeline ----------------
__global__ __launch_bounds__(256) void gather_kernel(
    const unsigned int* __restrict__ p_bf, const int* __restrict__ row_start,
    const int* __restrict__ bucket, const float* __restrict__ deg_out,
    float* __restrict__ dst, int n) {
    int row = blockIdx.x * 4 + (threadIdx.x >> 6);
    int lane = threadIdx.x & 63;
    if (row >= n) return;
    int beg = row_start[row], end = row_start[row + 1];
    float ax = 0.f, ay = 0.f;
    int idx = beg;
    for (; idx + 4 <= end; idx += 4) {
        int s0 = bucket[idx + 0];
        int s1 = bucket[idx + 1];
        int s2 = bucket[idx + 2];
        int s3 = bucket[idx + 3];
        unsigned int v0 = p_bf[(size_t)s0 * 64 + lane];
        unsigned int v1 = p_bf[(size_t)s1 * 64 + lane];
        unsigned int v2 = p_bf[(size_t)s2 * 64 + lane];
        unsigned int v3 = p_bf[(size_t)s3 * 64 + lane];
        ax += __uint_as_float(v0 << 16) + __uint_as_float(v1 << 16)
            + __uint_as_float(v2 << 16) + __uint_as_float(v3 << 16);
        ay += __uint_as_float(v0 & 0xffff0000u) + __uint_as_float(v1 & 0xffff0000u)
            + __uint_as_float(v2 & 0xffff0000u) + __uint_as_float(v3 & 0xffff0000u);
    }
    for (; idx < end; ++idx) {
        int s = bucket[idx];
        unsigned int v = p_bf[(size_t)s * 64 + lane];
        ax += __uint_as_float(v << 16);
        ay += __uint_as_float(v & 0xffff0000u);
    }
    float dinv = 1.0f / deg_out[row];
    float2 o;
    o.x = ax * dinv;
    o.y = ay * dinv;
    ((float2*)dst)[(size_t)row * 64 + lane] = o;
}

extern "C" void kernel_launch(void* const* d_in, const int* in_sizes, int n_in,
                              void* d_out, int out_size, void* d_ws, size_t ws_size,
                              hipStream_t stream) {
    const float* x_src = (const float*)d_in[0];
    const float* W_src = (const float*)d_in[2];
    const int* edge_src = (const int*)d_in[4];
    const int* edge_dst = (const int*)d_in[5];

    const int N_SRC = in_sizes[0] / D_SRC;
    const int N_DST = in_sizes[1] / D_SRC;
    const int E = in_sizes[4];

    float* out_dst = (float*)d_out;                          // [N_DST, 128]
    float* out_psrc = out_dst + (size_t)N_DST * D_REL;       // [N_SRC, 128]
    float* out_deg = out_psrc + (size_t)N_SRC * D_REL;       // [N_DST]

    int* deg_i = (int*)d_ws;               // N_DST
    int* incl = deg_i + N_DST;             // N_DST
    int* row_start = incl + N_DST;         // N_DST+1
    int* bsums = row_start + N_DST + 1;    // 128
    int* pos_arr = bsums + 128;            // E
    int* bucket = pos_arr + E;             // E
    size_t int_bytes = (size_t)(3 * N_DST + 1 + 128 + 2 * (size_t)E) * sizeof(int);
    size_t wt_off = (int_bytes + 255) & ~(size_t)255;
    bf16x8* Wt = (bf16x8*)((char*)d_ws + wt_off);            // 64 KB
    size_t pbf_off = wt_off + 65536;
    unsigned short* p_bf = (unsigned short*)((char*)d_ws + pbf_off);  // N_SRC*128 bf16

    // 1. zero deg_i
    zero_kernel<<<(N_DST + 255) / 256, 256, 0, stream>>>(deg_i, N_DST);
    // 2a. arrange W fragments (32x32x16 layout)
    prep_w_kernel<<<64, 64, 0, stream>>>(W_src, Wt);
    // 2b. projection (bf16 MFMA 32x32x16, LDS-free) + bf16 copy
    proj_mfma_kernel<<<(N_SRC + 127) / 128, 256, 0, stream>>>(
        x_src, Wt, out_psrc, p_bf, N_SRC);
    // 3. degree count + per-edge position
    count_kernel<<<(E + 255) / 256, 256, 0, stream>>>(edge_dst, deg_i, pos_arr, E);
    // 4. scan
    int nb = (N_DST + 1023) / 1024;
    scan_blocks<<<nb, 1024, 0, stream>>>(deg_i, incl, bsums, N_DST);
    scan_sums<<<1, 128, 0, stream>>>(bsums, nb);
    finalize_kernel<<<nb, 1024, 0, stream>>>(deg_i, incl, bsums, row_start, out_deg, N_DST, E);
    // 5. bucket fill (atomic-free)
    fill_kernel<<<(E + 255) / 256, 256, 0, stream>>>(edge_src, edge_dst, row_start, pos_arr, bucket, E);
    // 6. gather + normalize (bf16 source)
    gather_kernel<<<(N_DST + 3) / 4, 256, 0, stream>>>(
        (const unsigned int*)p_bf, row_start, bucket, out_deg, out_dst, N_DST);
}

// Round 5
// 151.064 us; speedup vs baseline: 1.0166x; 1.0166x over previous
//
#include <hip/hip_runtime.h>
#include <hip/hip_bf16.h>

#define D_SRC 256
#define D_REL 128

typedef __bf16 bf16x8 __attribute__((ext_vector_type(8)));
typedef float f32x4 __attribute__((ext_vector_type(4)));
typedef float f32x16 __attribute__((ext_vector_type(16)));

typedef const __attribute__((address_space(1))) void GASV;
typedef __attribute__((address_space(3))) void LASV;

// ---------------- zero scratch ----------------
__global__ void zero_kernel(int* __restrict__ p, int n) {
    int i = blockIdx.x * 256 + threadIdx.x;
    if (i < n) p[i] = 0;
}

// ---------------- prep: arrange W (fp32 [256][128]) into 32x32x16 B-fragment order ----------------
// Wt[(ks*4+n)*64 + lane] = bf16x8 { W[ks*16 + (lane>>5)*8 + j][n*32 + (lane&31)] , j=0..7 }
__global__ __launch_bounds__(64) void prep_w_kernel(const float* __restrict__ W,
                                                    bf16x8* __restrict__ Wt) {
    int c = blockIdx.x;            // 0..63 = ks*4 + n
    int ks = c >> 2, n = c & 3;
    int lane = threadIdx.x;
    int col = n * 32 + (lane & 31);
    int k0 = ks * 16 + (lane >> 5) * 8;
    bf16x8 v;
#pragma unroll
    for (int j = 0; j < 8; ++j) v[j] = (__bf16)W[(size_t)(k0 + j) * D_REL + col];
    Wt[c * 64 + lane] = v;
}

// ---------------- projection via 32x32x16 bf16 MFMA ----------------
// 4 waves/block, wave-private A staging via global_load_lds (pre-swizzled source),
// double-buffered, counted-vmcnt pipeline, NO barriers.
__global__ __launch_bounds__(256) void proj_mfma_kernel(
    const float* __restrict__ x, const bf16x8* __restrict__ Wt,
    float* __restrict__ out, unsigned short* __restrict__ out_bf, int M) {
    __shared__ float lds[2 * 4 * 2048];   // [buf][wave][32 rows x 64 floats] = 64 KB
    int tid = threadIdx.x;
    int wave = tid >> 6, lane = tid & 63;
    int r31 = lane & 31, h = lane >> 5;
    int row0 = blockIdx.x * 128 + wave * 32;

    float* buf0 = &lds[wave * 2048];
    float* buf1 = &lds[4 * 2048 + wave * 2048];

    // staging: instr j covers chunks ci = j*64+lane (16B each);
    // rl = ci>>4 (local row), qqp = ci&15 (physical 16B slot in row),
    // logical slot qql = qqp ^ ((rl&7)<<1)  [XOR swizzle, both-sides involution]
    auto stagef = [&](float* dstbase, int kt) {
#pragma unroll
        for (int j = 0; j < 8; ++j) {
            int ci = j * 64 + lane;
            int rl = ci >> 4;
            int qql = (ci & 15) ^ ((rl & 7) << 1);
            int srow = min(row0 + rl, M - 1);
            const float* src = x + (size_t)srow * D_SRC + kt * 64 + qql * 4;
            __builtin_amdgcn_global_load_lds((GASV*)src, (LASV*)(dstbase + j * 256),
                                             16, 0, 0);
        }
    };

    f32x16 acc[4];
#pragma unroll
    for (int n = 0; n < 4; ++n) acc[n] = (f32x16)(0.f);

    stagef(buf0, 0);

    const float* cur = buf0;
    float* nxt = buf1;
#pragma unroll
    for (int kt = 0; kt < 4; ++kt) {
        if (kt < 3) {
            stagef(nxt, kt + 1);
            asm volatile("s_waitcnt vmcnt(8)" ::: "memory");   // chunk kt landed
        } else {
            asm volatile("s_waitcnt vmcnt(0)" ::: "memory");
        }
        int sw = (r31 & 7) << 1;
#pragma unroll
        for (int st = 0; st < 4; ++st) {
            int ks = kt * 4 + st;
            bf16x8 b0 = Wt[(ks * 4 + 0) * 64 + lane];
            bf16x8 b1 = Wt[(ks * 4 + 1) * 64 + lane];
            bf16x8 b2 = Wt[(ks * 4 + 2) * 64 + lane];
            bf16x8 b3 = Wt[(ks * 4 + 3) * 64 + lane];
            int p0 = (st * 4 + h * 2 + 0) ^ sw;
            int p1 = (st * 4 + h * 2 + 1) ^ sw;
            f32x4 a0 = *(const f32x4*)(cur + r31 * 64 + p0 * 4);
            f32x4 a1 = *(const f32x4*)(cur + r31 * 64 + p1 * 4);
            bf16x8 af;
            af[0] = (__bf16)a0[0]; af[1] = (__bf16)a0[1];
            af[2] = (__bf16)a0[2]; af[3] = (__bf16)a0[3];
            af[4] = (__bf16)a1[0]; af[5] = (__bf16)a1[1];
            af[6] = (__bf16)a1[2]; af[7] = (__bf16)a1[3];
            acc[0] = __builtin_amdgcn_mfma_f32_32x32x16_bf16(af, b0, acc[0], 0, 0, 0);
            acc[1] = __builtin_amdgcn_mfma_f32_32x32x16_bf16(af, b1, acc[1], 0, 0, 0);
            acc[2] = __builtin_amdgcn_mfma_f32_32x32x16_bf16(af, b2, acc[2], 0, 0, 0);
            acc[3] = __builtin_amdgcn_mfma_f32_32x32x16_bf16(af, b3, acc[3], 0, 0, 0);
        }
        float* t = (float*)cur; cur = nxt; nxt = t;
    }

    // store: row = base + (reg&3) + 8*(reg>>2) + 4*half, col = n*32 + r31
    int rbase = blockIdx.x * 128 + wave * 32 + 4 * h;
#pragma unroll
    for (int n = 0; n < 4; ++n) {
#pragma unroll
        for (int reg = 0; reg < 16; ++reg) {
            int r = rbase + (reg & 3) + 8 * (reg >> 2);
            if (r < M) {
                float v = acc[n][reg];
                size_t o = (size_t)r * D_REL + n * 32 + r31;
                out[o] = v;
                out_bf[o] = __bfloat16_as_ushort(__float2bfloat16(v));
            }
        }
    }
}

// ---------------- degree count + per-edge bucket position ----------------
__global__ void count_kernel(const int* __restrict__ edge_dst, int* __restrict__ deg_i,
                             int* __restrict__ pos_arr, int E) {
    int e = blockIdx.x * 256 + threadIdx.x;
    if (e < E) pos_arr[e] = atomicAdd(&deg_i[edge_dst[e]], 1);
}

// ---------------- 2-level exclusive scan ----------------
__global__ __launch_bounds__(1024) void scan_blocks(
    const int* __restrict__ deg_i, int* __restrict__ incl,
    int* __restrict__ bsums, int n) {
    int i = blockIdx.x * 1024 + threadIdx.x;
    int v = (i < n) ? deg_i[i] : 0;
    int lane = threadIdx.x & 63;
    int wid = threadIdx.x >> 6;
    int x = v;
#pragma unroll
    for (int off = 1; off < 64; off <<= 1) {
        int y = __shfl_up(x, off, 64);
        if (lane >= off) x += y;
    }
    __shared__ int wsum[16];
    if (lane == 63) wsum[wid] = x;
    __syncthreads();
    if (wid == 0 && lane < 16) {
        int s = wsum[lane];
#pragma unroll
        for (int off = 1; off < 16; off <<= 1) {
            int y = __shfl_up(s, off, 64);
            if (lane >= off) s += y;
        }
        wsum[lane] = s;
    }
    __syncthreads();
    int add = (wid > 0) ? wsum[wid - 1] : 0;
    x += add;
    if (i < n) incl[i] = x;
    if (threadIdx.x == 1023) bsums[blockIdx.x] = x;
}

__global__ __launch_bounds__(128) void scan_sums(int* __restrict__ bs, int nb) {
    __shared__ int tmp[128];
    int t = threadIdx.x;
    int v = (t < nb) ? bs[t] : 0;
    tmp[t] = v;
    __syncthreads();
    for (int off = 1; off < 128; off <<= 1) {
        int y = 0;
        if (t >= off) y = tmp[t - off];
        __syncthreads();
        tmp[t] += y;
        __syncthreads();
    }
    if (t < nb) bs[t] = tmp[t] - v;  // exclusive
}

__global__ __launch_bounds__(1024) void finalize_kernel(
    const int* __restrict__ deg_i, const int* __restrict__ incl,
    const int* __restrict__ bsums, int* __restrict__ row_start,
    float* __restrict__ deg_out, int n, int E) {
    int i = blockIdx.x * 1024 + threadIdx.x;
    if (i < n) {
        int off = bsums[blockIdx.x];
        row_start[i] = off + incl[i] - deg_i[i];
        deg_out[i] = (float)max(deg_i[i], 1);
    }
    if (i == 0) row_start[n] = E;
}

// ---------------- bucket fill (atomic-free) ----------------
__global__ void fill_kernel(const int* __restrict__ edge_src,
                            const int* __restrict__ edge_dst,
                            const int* __restrict__ row_start,
                            const int* __restrict__ pos_arr,
                            int* __restrict__ bucket, int E) {
    int e = blockIdx.x * 256 + threadIdx.x;
    if (e < E) {
        int d = edge_dst[e];
        bucket[row_start[d] + pos_arr[e]] = edge_src[e];
    }
}

// ---------------- gather: one wave per dst row, bf16 source, 4-deep pipeline ----------------
__global__ __launch_bounds__(256) void gather_kernel(
    const unsigned int* __restrict__ p_bf, const int* __restrict__ row_start,
    const int* __restrict__ bucket, const float* __restrict__ deg_out,
    float* __restrict__ dst, int n) {
    int row = blockIdx.x * 4 + (threadIdx.x >> 6);
    int lane = threadIdx.x & 63;
    if (row >= n) return;
    int beg = row_start[row], end = row_start[row + 1];
    float ax = 0.f, ay = 0.f;
    int idx = beg;
    for (; idx + 4 <= end; idx += 4) {
        int s0 = bucket[idx + 0];
        int s1 = bucket[idx + 1];
        int s2 = bucket[idx + 2];
        int s3 = bucket[idx + 3];
        unsigned int v0 = p_bf[(size_t)s0 * 64 + lane];
        unsigned int v1 = p_bf[(size_t)s1 * 64 + lane];
        unsigned int v2 = p_bf[(size_t)s2 * 64 + lane];
        unsigned int v3 = p_bf[(size_t)s3 * 64 + lane];
        ax += __uint_as_float(v0 << 16) + __uint_as_float(v1 << 16)
            + __uint_as_float(v2 << 16) + __uint_as_float(v3 << 16);
        ay += __uint_as_float(v0 & 0xffff0000u) + __uint_as_float(v1 & 0xffff0000u)
            + __uint_as_float(v2 & 0xffff0000u) + __uint_as_float(v3 & 0xffff0000u);
    }
    for (; idx < end; ++idx) {
        int s = bucket[idx];
        unsigned int v = p_bf[(size_t)s * 64 + lane];
        ax += __uint_as_float(v << 16);
        ay += __uint_as_float(v & 0xffff0000u);
    }
    float dinv = 1.0f / deg_out[row];
    float2 o;
    o.x = ax * dinv;
    o.y = ay * dinv;
    ((float2*)dst)[(size_t)row * 64 + lane] = o;
}

extern "C" void kernel_launch(void* const* d_in, const int* in_sizes, int n_in,
                              void* d_out, int out_size, void* d_ws, size_t ws_size,
                              hipStream_t stream) {
    const float* x_src = (const float*)d_in[0];
    const float* W_src = (const float*)d_in[2];
    const int* edge_src = (const int*)d_in[4];
    const int* edge_dst = (const int*)d_in[5];

    const int N_SRC = in_sizes[0] / D_SRC;
    const int N_DST = in_sizes[1] / D_SRC;
    const int E = in_sizes[4];

    float* out_dst = (float*)d_out;                          // [N_DST, 128]
    float* out_psrc = out_dst + (size_t)N_DST * D_REL;       // [N_SRC, 128]
    float* out_deg = out_psrc + (size_t)N_SRC * D_REL;       // [N_DST]

    int* deg_i = (int*)d_ws;               // N_DST
    int* incl = deg_i + N_DST;             // N_DST
    int* row_start = incl + N_DST;         // N_DST+1
    int* bsums = row_start + N_DST + 1;    // 128
    int* pos_arr = bsums + 128;            // E
    int* bucket = pos_arr + E;             // E
    size_t int_bytes = (size_t)(3 * N_DST + 1 + 128 + 2 * (size_t)E) * sizeof(int);
    size_t wt_off = (int_bytes + 255) & ~(size_t)255;
    bf16x8* Wt = (bf16x8*)((char*)d_ws + wt_off);            // 64 KB
    size_t pbf_off = wt_off + 65536;
    unsigned short* p_bf = (unsigned short*)((char*)d_ws + pbf_off);  // N_SRC*128 bf16

    // 1. zero deg_i
    zero_kernel<<<(N_DST + 255) / 256, 256, 0, stream>>>(deg_i, N_DST);
    // 2a. arrange W fragments (32x32x16 layout)
    prep_w_kernel<<<64, 64, 0, stream>>>(W_src, Wt);
    // 2b. projection (bf16 MFMA 32x32x16, global_load_lds staged) + bf16 copy
    proj_mfma_kernel<<<(N_SRC + 127) / 128, 256, 0, stream>>>(
        x_src, Wt, out_psrc, p_bf, N_SRC);
    // 3. degree count + per-edge position
    count_kernel<<<(E + 255) / 256, 256, 0, stream>>>(edge_dst, deg_i, pos_arr, E);
    // 4. scan
    int nb = (N_DST + 1023) / 1024;
    scan_blocks<<<nb, 1024, 0, stream>>>(deg_i, incl, bsums, N_DST);
    scan_sums<<<1, 128, 0, stream>>>(bsums, nb);
    finalize_kernel<<<nb, 1024, 0, stream>>>(deg_i, incl, bsums, row_start, out_deg, N_DST, E);
    // 5. bucket fill (atomic-free)
    fill_kernel<<<(E + 255) / 256, 256, 0, stream>>>(edge_src, edge_dst, row_start, pos_arr, bucket, E);
    // 6. gather + normalize (bf16 source)
    gather_kernel<<<(N_DST + 3) / 4, 256, 0, stream>>>(
        (const unsigned int*)p_bf, row_start, bucket, out_deg, out_dst, N_DST);
}